// Round 19
// baseline (391.555 us; speedup 1.0000x reference)
//
#include <hip/hip_runtime.h>

// SSHA block. Round 19 (everything else = round 18):
//   k_tconv rewritten LDS-free: A-fragments are direct bf16x8 loads from
//   y2b (k-contiguous per kt-chunk), per-lane bounds guard (OOB -> 0; rows
//   >= 7200 discarded by the epilogue guard). Deletes the 71.7 KB LDS slab,
//   the staging loop and the barrier -> occupancy 2 -> ~4+ blocks/CU.
// Shapes: N=16, T=288, V=25, C=128, S=8, IC=16, W=3, U=75, TP=290.

#define NN 16
#define TT 288
#define VV 25
#define CC 128
#define SS 8
#define UU 75
#define TP 290
#define EPSF 1e-5f

typedef __attribute__((ext_vector_type(8))) short bf16x8;
typedef __attribute__((ext_vector_type(4))) float f32x4;

static __device__ __forceinline__ ushort f2bf(float f) {
  uint u = __float_as_uint(f);
  u = (u + 0x7FFFu + ((u >> 16) & 1u)) >> 16;
  return (ushort)u;
}
static __device__ __forceinline__ float bf2f(ushort u) {
  return __uint_as_float((uint)u << 16);
}

// ---------------- K-1: x -> bf16 (once) ----------------
__global__ __launch_bounds__(256) void k_xcvt(const float* __restrict__ x,
                                              ushort* __restrict__ xb) {
  size_t i = (size_t)blockIdx.x * 256 + threadIdx.x;  // 1,843,200 thr x 8 el
  const float4* xp = (const float4*)x + i * 2;
  float4 a0 = xp[0], a1 = xp[1];
  uint4 pk;
  pk.x = (uint)f2bf(a0.x) | ((uint)f2bf(a0.y) << 16);
  pk.y = (uint)f2bf(a0.z) | ((uint)f2bf(a0.w) << 16);
  pk.z = (uint)f2bf(a1.x) | ((uint)f2bf(a1.y) << 16);
  pk.w = (uint)f2bf(a1.z) | ((uint)f2bf(a1.w) << 16);
  *(uint4*)&xb[i * 8] = pk;
}

// ---------------- K0: all weight converts + qb pad rows ----------------
__global__ __launch_bounds__(256) void k_prep(
    const float* __restrict__ w_out, const float* __restrict__ w_k,
    const float* __restrict__ w_q, const float* __restrict__ w_ff,
    const float* __restrict__ w_t, const float* __restrict__ b_q,
    ushort* __restrict__ wb, ushort* __restrict__ wkqb,
    ushort* __restrict__ wffb, ushort* __restrict__ wbt,
    ushort* __restrict__ qb) {
  int i = blockIdx.x * 256 + threadIdx.x;  // 397312 total
  if (i < 131072) {
    int j = i >> 7, c = i & 127;
    int s = j >> 7, o = j & 127;
    wb[i] = f2bf(w_out[(o << 10) + (s << 7) + c]);
  } else if (i < 163840) {
    int j = i - 131072;
    if (j < 16384) wkqb[j] = f2bf(w_k[j]);
    else wkqb[j] = f2bf(w_q[j - 16384]);
  } else if (i < 180224) {
    int j = i - 163840;
    wffb[j] = f2bf(w_ff[j]);
  } else if (i < 294912) {
    int j = i - 180224;
    int o = j / 896;
    int rem = j - o * 896;
    int c = rem / 7, kt = rem - c * 7;
    wbt[o * 896 + kt * 128 + c] = f2bf(w_t[j]);
  } else {
    int j = i - 294912;  // 102400: qb bias-only pad rows (tp=0, 289)
    int o = j & 127;
    int r = j >> 7;
    int v = r % 25;
    int e = (r / 25) & 1;
    int n = r / 50;
    int tp = e ? 289 : 0;
    qb[((size_t)((n * TP + tp) * VV + v) << 7) + o] = f2bf(b_q[o]);
  }
}

// ---------------- K1: k/q 1x1 convs as bf16 MFMA GEMM (LDS-free, xb input) ----------------
__global__ __launch_bounds__(256) void k_qkg(
    const ushort* __restrict__ xb, const ushort* __restrict__ wkqb,
    const float* __restrict__ b_k, const float* __restrict__ b_q,
    ushort* __restrict__ kb, ushort* __restrict__ qb) {
  const int gm0 = blockIdx.x << 7, by = blockIdx.y;
  const int tid = threadIdx.x;
  const int lane = tid & 63, wid = tid >> 6;
  const int wm = wid >> 1, wn = wid & 1;
  const int l15 = lane & 15, l4 = lane >> 4;
  const ushort* wsrc = wkqb + by * 16384;
  f32x4 acc[4][4] = {};
#pragma unroll
  for (int g = 0; g < 4; ++g) {
    const int k0 = g * 32 + l4 * 8;
    bf16x8 af[4], bfr[4];
#pragma unroll
    for (int mi = 0; mi < 4; ++mi)
      af[mi] = *(const bf16x8*)&xb[((size_t)(gm0 + wm * 64 + mi * 16 + l15))
                                       * 128 + k0];
#pragma unroll
    for (int ni = 0; ni < 4; ++ni)
      bfr[ni] = *(const bf16x8*)&wsrc[(wn * 64 + ni * 16 + l15) * 128 + k0];
#pragma unroll
    for (int mi = 0; mi < 4; ++mi)
#pragma unroll
      for (int ni = 0; ni < 4; ++ni)
        acc[mi][ni] = __builtin_amdgcn_mfma_f32_16x16x32_bf16(
            af[mi], bfr[ni], acc[mi][ni], 0, 0, 0);
  }
  const float* bias = by ? b_q : b_k;
#pragma unroll
  for (int ni = 0; ni < 4; ++ni) {
    int col = wn * 64 + ni * 16 + l15;
    float bb = bias[col];
#pragma unroll
    for (int mi = 0; mi < 4; ++mi) {
#pragma unroll
      for (int reg = 0; reg < 4; ++reg) {
        int row = gm0 + wm * 64 + mi * 16 + (l4 << 2) + reg;
        ushort val = f2bf(acc[mi][ni][reg] + bb);
        if (by == 0) {
          kb[((size_t)row << 7) + col] = val;
        } else {
          int n = row / 7200;
          qb[((size_t)(row + n * 50 + 25) << 7) + col] = val;
        }
      }
    }
  }
}

// ---------------- K2: scores (bf16 MFMA) + fused softmax -> attTb bf16 ----------------
// attTb[n][s][v(25)][u'(96)] with u' = w*32+vp, zero at vp>=25.
__global__ __launch_bounds__(512) void k_scores(
    const ushort* __restrict__ kb, const ushort* __restrict__ qb,
    const float* __restrict__ alphas, const float* __restrict__ att0,
    ushort* __restrict__ attTb) {
  __shared__ float red[8][2640];  // [wave][u(80) * 33 + v(32)]
  __shared__ float scl[1875];
  __shared__ float mx[25];
  __shared__ float den[25];
  const int bx = blockIdx.x;
  const int n = bx >> 3, s = bx & 7;
  const int tid = threadIdx.x;
  const int lane = tid & 63, wid = tid >> 6;
  const int l15 = lane & 15, l4 = lane >> 4;
  const int dt = l4 >> 1;
  const int sic = s * 16 + (l4 & 1) * 8;
  int qoff[5];
#pragma unroll
  for (int tu = 0; tu < 5; ++tu) {
    int u = tu * 16 + l15;
    int w = u / 25, vp = u - w * 25;
    qoff[tu] = (w * 25 + vp) * 128 + sic;
  }
  const bool qv4 = (64 + l15) < 75;
  const bool kv1 = (16 + l15) < 25;
  int koff0 = l15 * 128 + sic;
  int koff1 = (16 + l15) * 128 + sic;
  const ushort* qbase = qb + (size_t)n * 928000 + (size_t)dt * 3200;
  const ushort* kbase = kb + (size_t)n * 921600 + (size_t)dt * 3200;
  f32x4 acc[5][2] = {};
  const bf16x8 zf = {};
  for (int kk = wid; kk < 144; kk += 8) {
    const ushort* qp = qbase + kk * 6400;
    const ushort* kp = kbase + kk * 6400;
    bf16x8 a[5], b[2];
#pragma unroll
    for (int tu = 0; tu < 4; ++tu) a[tu] = *(const bf16x8*)(qp + qoff[tu]);
    a[4] = qv4 ? *(const bf16x8*)(qp + qoff[4]) : zf;
    b[0] = *(const bf16x8*)(kp + koff0);
    b[1] = kv1 ? *(const bf16x8*)(kp + koff1) : zf;
#pragma unroll
    for (int tu = 0; tu < 5; ++tu)
#pragma unroll
      for (int tv = 0; tv < 2; ++tv)
        acc[tu][tv] = __builtin_amdgcn_mfma_f32_16x16x32_bf16(
            a[tu], b[tv], acc[tu][tv], 0, 0, 0);
  }
#pragma unroll
  for (int tu = 0; tu < 5; ++tu)
#pragma unroll
    for (int tv = 0; tv < 2; ++tv) {
#pragma unroll
      for (int reg = 0; reg < 4; ++reg)
        red[wid][(tu * 16 + l4 * 4 + reg) * 33 + tv * 16 + l15] =
            acc[tu][tv][reg];
    }
  __syncthreads();
  const float inv = 1.0f / 4608.0f;
  for (int i = tid; i < 1875; i += 512) {
    int u = i / 25, v = i - u * 25;
    float a = 0.f;
#pragma unroll
    for (int w = 0; w < 8; ++w) a += red[w][u * 33 + v];
    scl[i] = a * inv;
  }
  __syncthreads();
  if (tid < 25) {
    float m = -1e30f;
    for (int u = 0; u < 75; ++u) m = fmaxf(m, scl[u * 25 + tid]);
    float d = 0.f;
    for (int u = 0; u < 75; ++u) d += expf(scl[u * 25 + tid] - m);
    mx[tid] = m;
    den[tid] = d;
  }
  __syncthreads();
  const float alpha = alphas[s];
  ushort* op = attTb + (size_t)bx * 2400;
  for (int i = tid; i < 2400; i += 512) {
    int v = i / 96, u = i - v * 96;
    int w = u >> 5, vp = u & 31;
    float val = 0.f;
    if (vp < 25) {
      int uo = w * 25 + vp;
      val = expf(scl[uo * 25 + v] - mx[v]) / den[v] * alpha +
            att0[(s * 75 + uo) * 25 + v];
    }
    op[i] = f2bf(val);
  }
}

// ---------------- K3: attention-apply + out conv + FF conv (triple MFMA, TB=2) ----------------
__global__ __launch_bounds__(256, 3) void k_attn3(
    const float* __restrict__ x, const ushort* __restrict__ xb,
    const ushort* __restrict__ attTb, const ushort* __restrict__ wb,
    const float* __restrict__ b_out, const float* __restrict__ g_out,
    const float* __restrict__ beta_out, const float* __restrict__ m_out,
    const float* __restrict__ v_out, const ushort* __restrict__ wffb,
    const float* __restrict__ b_ff, const float* __restrict__ g_ff,
    const float* __restrict__ beta_ff, const float* __restrict__ m_ff,
    const float* __restrict__ v_ff, ushort* __restrict__ y2b) {
  __shared__ __align__(16) uint4 Xt4[16 * 129];  // [chunk][c pad129]
  __shared__ __align__(16) ushort Yl[2][32 * 136];
  const int t0 = blockIdx.x * 2, n = blockIdx.y;
  const int tid = threadIdx.x;
  // stage Xt from xb: chunk = r*4 + vp0/8 (r = t-row, tr = t0+r-1).
  for (int i = tid; i < 2048; i += 256) {
    int c = i & 127, chunk = i >> 7;
    int r = chunk >> 2, vp0 = (chunk & 3) * 8;
    int tr = t0 + r - 1;
    bool valid = (tr >= 0 && tr < TT);
    const ushort* xr = xb + (((size_t)(n * TT + tr) * VV)) * 128 + c;
    ushort p[8];
#pragma unroll
    for (int j = 0; j < 8; ++j) {
      int vp = vp0 + j;
      p[j] = (valid && vp < 25) ? xr[vp * 128] : (ushort)0;
    }
    uint4 pk;
    pk.x = (uint)p[0] | ((uint)p[1] << 16);
    pk.y = (uint)p[2] | ((uint)p[3] << 16);
    pk.z = (uint)p[4] | ((uint)p[5] << 16);
    pk.w = (uint)p[6] | ((uint)p[7] << 16);
    Xt4[chunk * 129 + c] = pk;
  }
  __syncthreads();
  const int lane = tid & 63, wid = tid >> 6;
  const int l15 = lane & 15, l4 = lane >> 4;
  const bf16x8 zf = {};
  f32x4 accO[2][2][2] = {};  // [tt][mi(o)][nj(v)]
  const ushort* Avn = attTb + (size_t)n * 19200;
  const int c0r = wid * 32 + l15, c1r = wid * 32 + 16 + l15;

  // step1: accY[tt][cmi][vnj] = D[c][v], A = X rows c, B = Av rows v.
  auto step1 = [&](int s, f32x4 (&accY)[2][2][2]) {
    const ushort* AvS = Avn + s * 2400;
#pragma unroll
    for (int ks = 0; ks < 3; ++ks) {
      int u0 = ks * 32 + l4 * 8;
      bf16x8 av0 = *(const bf16x8*)&AvS[l15 * 96 + u0];
      int r1 = 16 + l15;
      bf16x8 av1 = *(const bf16x8*)&AvS[(r1 <= 24 ? r1 : 24) * 96 + u0];
      if (l15 > 8) av1 = zf;  // v >= 25 -> zero row
#pragma unroll
      for (int tt = 0; tt < 2; ++tt) {
        int ch = (tt + ks) * 4 + l4;
        bf16x8 xb0 = *(const bf16x8*)&Xt4[ch * 129 + c0r];
        bf16x8 xb1 = *(const bf16x8*)&Xt4[ch * 129 + c1r];
        accY[tt][0][0] = __builtin_amdgcn_mfma_f32_16x16x32_bf16(xb0, av0, accY[tt][0][0], 0, 0, 0);
        accY[tt][0][1] = __builtin_amdgcn_mfma_f32_16x16x32_bf16(xb0, av1, accY[tt][0][1], 0, 0, 0);
        accY[tt][1][0] = __builtin_amdgcn_mfma_f32_16x16x32_bf16(xb1, av0, accY[tt][1][0], 0, 0, 0);
        accY[tt][1][1] = __builtin_amdgcn_mfma_f32_16x16x32_bf16(xb1, av1, accY[tt][1][1], 0, 0, 0);
      }
    }
  };

  f32x4 accYc[2][2][2] = {};
  step1(0, accYc);
#pragma unroll
  for (int s = 0; s < 8; ++s) {
    __syncthreads();  // previous step-2 readers done with Yl
#pragma unroll
    for (int tt = 0; tt < 2; ++tt)
#pragma unroll
      for (int cmi = 0; cmi < 2; ++cmi)
#pragma unroll
        for (int vnj = 0; vnj < 2; ++vnj) {
          ushort4 p;
          p.x = f2bf(accYc[tt][cmi][vnj][0]);
          p.y = f2bf(accYc[tt][cmi][vnj][1]);
          p.z = f2bf(accYc[tt][cmi][vnj][2]);
          p.w = f2bf(accYc[tt][cmi][vnj][3]);
          *(ushort4*)&Yl[tt][(vnj * 16 + l15) * 136 + wid * 32 + cmi * 16 +
                             (l4 << 2)] = p;
        }
    __syncthreads();
    // pipelined: step1(s+1) + step2(s) between barriers (independent work)
    __builtin_amdgcn_s_setprio(1);
    f32x4 accYn[2][2][2] = {};
    if (s < 7) step1(s + 1, accYn);
    const ushort* wS = wb + s * 16384;
#pragma unroll
    for (int kc = 0; kc < 4; ++kc) {
      int c0 = kc * 32 + l4 * 8;
      bf16x8 wf0 = *(const bf16x8*)&wS[(wid * 32 + l15) * 128 + c0];
      bf16x8 wf1 = *(const bf16x8*)&wS[(wid * 32 + 16 + l15) * 128 + c0];
#pragma unroll
      for (int tt = 0; tt < 2; ++tt) {
        bf16x8 yb0 = *(const bf16x8*)&Yl[tt][l15 * 136 + c0];
        bf16x8 yb1 = *(const bf16x8*)&Yl[tt][(16 + l15) * 136 + c0];
        accO[tt][0][0] = __builtin_amdgcn_mfma_f32_16x16x32_bf16(wf0, yb0, accO[tt][0][0], 0, 0, 0);
        accO[tt][0][1] = __builtin_amdgcn_mfma_f32_16x16x32_bf16(wf0, yb1, accO[tt][0][1], 0, 0, 0);
        accO[tt][1][0] = __builtin_amdgcn_mfma_f32_16x16x32_bf16(wf1, yb0, accO[tt][1][0], 0, 0, 0);
        accO[tt][1][1] = __builtin_amdgcn_mfma_f32_16x16x32_bf16(wf1, yb1, accO[tt][1][1], 0, 0, 0);
      }
    }
    __builtin_amdgcn_s_setprio(0);
#pragma unroll
    for (int tt = 0; tt < 2; ++tt)
#pragma unroll
      for (int mi = 0; mi < 2; ++mi)
#pragma unroll
        for (int nj = 0; nj < 2; ++nj)
          accYc[tt][mi][nj] = accYn[tt][mi][nj];
  }
  // ---- y1 epilogue: BN + leaky(x + .), write bf16 to Yl (v>=25 rows = 0) ----
  __syncthreads();  // last step-2 Yl reads complete
#pragma unroll
  for (int tt = 0; tt < 2; ++tt) {
    int t = t0 + tt;
#pragma unroll
    for (int nj = 0; nj < 2; ++nj) {
      int v = nj * 16 + l15;
      ushort4 pv[2];
      if (v < 25) {
        size_t rowbase = (((size_t)(n * TT + t) * VV + v)) * 128 + wid * 32;
#pragma unroll
        for (int mi = 0; mi < 2; ++mi) {
          int ob = mi * 16 + (l4 << 2);
          int og = wid * 32 + ob;
          float4 gg = *(const float4*)&g_out[og];
          float4 vv = *(const float4*)&v_out[og];
          float4 mm = *(const float4*)&m_out[og];
          float4 be = *(const float4*)&beta_out[og];
          float4 bo = *(const float4*)&b_out[og];
          float4 xv = *(const float4*)&x[rowbase + ob];
          float s1, a;
          s1 = gg.x * rsqrtf(vv.x + EPSF);
          a = (accO[tt][mi][nj][0] + bo.x) * s1 + (be.x - mm.x * s1) + xv.x;
          pv[mi].x = f2bf(a > 0.f ? a : 0.1f * a);
          s1 = gg.y * rsqrtf(vv.y + EPSF);
          a = (accO[tt][mi][nj][1] + bo.y) * s1 + (be.y - mm.y * s1) + xv.y;
          pv[mi].y = f2bf(a > 0.f ? a : 0.1f * a);
          s1 = gg.z * rsqrtf(vv.z + EPSF);
          a = (accO[tt][mi][nj][2] + bo.z) * s1 + (be.z - mm.z * s1) + xv.z;
          pv[mi].z = f2bf(a > 0.f ? a : 0.1f * a);
          s1 = gg.w * rsqrtf(vv.w + EPSF);
          a = (accO[tt][mi][nj][3] + bo.w) * s1 + (be.w - mm.w * s1) + xv.w;
          pv[mi].w = f2bf(a > 0.f ? a : 0.1f * a);
        }
      } else {
        pv[0] = make_ushort4(0, 0, 0, 0);
        pv[1] = make_ushort4(0, 0, 0, 0);
      }
#pragma unroll
      for (int mi = 0; mi < 2; ++mi)
        *(ushort4*)&Yl[tt][v * 136 + wid * 32 + mi * 16 + (l4 << 2)] = pv[mi];
    }
  }
  __syncthreads();
  // ---- step 3: FF = W_ff . y1 (K=128) ----
  f32x4 accF[2][2][2] = {};  // [tt][mi(o)][nj(v)]
#pragma unroll
  for (int kc = 0; kc < 4; ++kc) {
    int c0 = kc * 32 + l4 * 8;
    bf16x8 wf0 = *(const bf16x8*)&wffb[(wid * 32 + l15) * 128 + c0];
    bf16x8 wf1 = *(const bf16x8*)&wffb[(wid * 32 + 16 + l15) * 128 + c0];
#pragma unroll
    for (int tt = 0; tt < 2; ++tt) {
      bf16x8 yb0 = *(const bf16x8*)&Yl[tt][l15 * 136 + c0];
      bf16x8 yb1 = *(const bf16x8*)&Yl[tt][(16 + l15) * 136 + c0];
      accF[tt][0][0] = __builtin_amdgcn_mfma_f32_16x16x32_bf16(wf0, yb0, accF[tt][0][0], 0, 0, 0);
      accF[tt][0][1] = __builtin_amdgcn_mfma_f32_16x16x32_bf16(wf0, yb1, accF[tt][0][1], 0, 0, 0);
      accF[tt][1][0] = __builtin_amdgcn_mfma_f32_16x16x32_bf16(wf1, yb0, accF[tt][1][0], 0, 0, 0);
      accF[tt][1][1] = __builtin_amdgcn_mfma_f32_16x16x32_bf16(wf1, yb1, accF[tt][1][1], 0, 0, 0);
    }
  }
  // ---- ff epilogue: y2b = bf16(leaky(x + BN_ff(FF + b_ff))) ----
#pragma unroll
  for (int tt = 0; tt < 2; ++tt) {
    int t = t0 + tt;
#pragma unroll
    for (int nj = 0; nj < 2; ++nj) {
      int v = nj * 16 + l15;
      if (v < 25) {
        size_t rowbase = (((size_t)(n * TT + t) * VV + v)) * 128 + wid * 32;
#pragma unroll
        for (int mi = 0; mi < 2; ++mi) {
          int ob = mi * 16 + (l4 << 2);
          int og = wid * 32 + ob;
          float4 gg = *(const float4*)&g_ff[og];
          float4 vv = *(const float4*)&v_ff[og];
          float4 mm = *(const float4*)&m_ff[og];
          float4 be = *(const float4*)&beta_ff[og];
          float4 bo = *(const float4*)&b_ff[og];
          float4 xv = *(const float4*)&x[rowbase + ob];
          ushort4 r;
          float s1, a;
          s1 = gg.x * rsqrtf(vv.x + EPSF);
          a = (accF[tt][mi][nj][0] + bo.x) * s1 + (be.x - mm.x * s1) + xv.x;
          r.x = f2bf(a > 0.f ? a : 0.1f * a);
          s1 = gg.y * rsqrtf(vv.y + EPSF);
          a = (accF[tt][mi][nj][1] + bo.y) * s1 + (be.y - mm.y * s1) + xv.y;
          r.y = f2bf(a > 0.f ? a : 0.1f * a);
          s1 = gg.z * rsqrtf(vv.z + EPSF);
          a = (accF[tt][mi][nj][2] + bo.z) * s1 + (be.z - mm.z * s1) + xv.z;
          r.z = f2bf(a > 0.f ? a : 0.1f * a);
          s1 = gg.w * rsqrtf(vv.w + EPSF);
          a = (accF[tt][mi][nj][3] + bo.w) * s1 + (be.w - mm.w * s1) + xv.w;
          r.w = f2bf(a > 0.f ? a : 0.1f * a);
          *(ushort4*)&y2b[rowbase + ob] = r;
        }
      }
    }
  }
}

// ---------------- K5: temporal conv as bf16 MFMA GEMM (LDS-free, y2b input) ----------------
// Grid (57, 16). 4 waves (2x2), 64x64 each. A-fragments direct from y2b
// (k-contiguous within each kt chunk); per-lane bounds guard -> 0.
__global__ __launch_bounds__(256) void k_tconv(
    const ushort* __restrict__ y2b, const float* __restrict__ x,
    const ushort* __restrict__ wbt, const float* __restrict__ b_t,
    const float* __restrict__ g_t, const float* __restrict__ beta_t,
    const float* __restrict__ m_t, const float* __restrict__ v_t,
    float* __restrict__ out) {
  const int n = blockIdx.y;
  const int r0 = blockIdx.x << 7;
  const int tid = threadIdx.x;
  const int lane = tid & 63, wid = tid >> 6;
  const int wm = wid >> 1, wn = wid & 1;
  const int l15 = lane & 15, l4 = lane >> 4;
  const ushort* y2n = y2b + (size_t)n * 7200 * 128;
  const bf16x8 zf = {};
  f32x4 acc[4][4] = {};
  for (int kt = 0; kt < 7; ++kt) {
    const int shift = 25 * (kt - 3);
    bf16x8 bfr[4][4];
#pragma unroll
    for (int ni = 0; ni < 4; ++ni) {
      const ushort* bp =
          wbt + (size_t)(wn * 64 + ni * 16 + l15) * 896 + kt * 128 + l4 * 8;
#pragma unroll
      for (int cc0 = 0; cc0 < 4; ++cc0)
        bfr[ni][cc0] = *(const bf16x8*)(bp + cc0 * 32);
    }
#pragma unroll
    for (int cc0 = 0; cc0 < 4; ++cc0) {
      bf16x8 af[4];
#pragma unroll
      for (int mi = 0; mi < 4; ++mi) {
        int row = r0 + wm * 64 + mi * 16 + l15;
        int src = row + shift;
        af[mi] = (src >= 0 && src < 7200)
                     ? *(const bf16x8*)&y2n[(size_t)src * 128 + cc0 * 32 +
                                            l4 * 8]
                     : zf;
      }
#pragma unroll
      for (int mi = 0; mi < 4; ++mi)
#pragma unroll
        for (int ni = 0; ni < 4; ++ni)
          acc[mi][ni] = __builtin_amdgcn_mfma_f32_16x16x32_bf16(
              af[mi], bfr[ni][cc0], acc[mi][ni], 0, 0, 0);
    }
  }
#pragma unroll
  for (int ni = 0; ni < 4; ++ni) {
    int o = wn * 64 + ni * 16 + l15;
    float s1 = g_t[o] * rsqrtf(v_t[o] + EPSF);
    float sh = beta_t[o] - m_t[o] * s1;
    float bb = b_t[o];
#pragma unroll
    for (int mi = 0; mi < 4; ++mi) {
#pragma unroll
      for (int reg = 0; reg < 4; ++reg) {
        int grow = r0 + wm * 64 + mi * 16 + (l4 << 2) + reg;
        if (grow < 7200) {
          size_t idx = (((size_t)n * 7200 + grow) << 7) + o;
          float z = (acc[mi][ni][reg] + bb) * s1 + sh;
          z += bf2f(y2b[idx]);
          z = z > 0.f ? z : 0.1f * z;
          z += x[idx];
          out[idx] = z > 0.f ? z : 0.f;
        }
      }
    }
  }
}

extern "C" void kernel_launch(void* const* d_in, const int* in_sizes, int n_in,
                              void* d_out, int out_size, void* d_ws, size_t ws_size,
                              hipStream_t stream) {
  const float* x      = (const float*)d_in[0];
  const float* w_k    = (const float*)d_in[1];
  const float* b_k    = (const float*)d_in[2];
  const float* w_q    = (const float*)d_in[3];
  const float* b_q    = (const float*)d_in[4];
  const float* alphas = (const float*)d_in[5];
  const float* att0   = (const float*)d_in[6];
  const float* w_out  = (const float*)d_in[7];
  const float* b_out  = (const float*)d_in[8];
  const float* g_out  = (const float*)d_in[9];
  const float* be_out = (const float*)d_in[10];
  const float* m_out  = (const float*)d_in[11];
  const float* v_out  = (const float*)d_in[12];
  const float* w_ff   = (const float*)d_in[13];
  const float* b_ff   = (const float*)d_in[14];
  const float* g_ff   = (const float*)d_in[15];
  const float* be_ff  = (const float*)d_in[16];
  const float* m_ff   = (const float*)d_in[17];
  const float* v_ff   = (const float*)d_in[18];
  const float* w_t    = (const float*)d_in[19];
  const float* b_t    = (const float*)d_in[20];
  const float* g_t    = (const float*)d_in[21];
  const float* be_t   = (const float*)d_in[22];
  const float* m_t    = (const float*)d_in[23];
  const float* v_t    = (const float*)d_in[24];

  float* ws = (float*)d_ws;
  // Region plan (floats), total 32,108,288 = round-1 proven footprint:
  float* qfull = ws;               // [0, 14848000)   qb bf16
  float* kfull = ws + 14848000;    // [.., +14745600) kb bf16 (lo, -> y2b) + xb (hi)
  float* part  = ws + 29593600;    // [.., +2160000)  wb/wkqb/wffb bf16
  float* attr  = ws + 31753600;    // [.., +240000)   attTb bf16 (307200 sh)
  float* wtr   = ws + 31993600;    // [.., +114688)   wbt bf16
  ushort* qbb   = (ushort*)qfull;
  ushort* kbb   = (ushort*)kfull;              // 14,745,600 shorts
  ushort* xbb   = (ushort*)kfull + 14745600;   // 14,745,600 shorts
  ushort* y2b   = kbb;  // kb dead after k_scores
  ushort* wb    = (ushort*)part;            // 131072 shorts
  ushort* wkqb  = (ushort*)part + 131072;   //  32768 shorts
  ushort* wffb  = (ushort*)part + 163840;   //  16384 shorts
  ushort* attTb = (ushort*)attr;
  ushort* wbt   = (ushort*)wtr;
  float* outp = (float*)d_out;

  k_xcvt<<<7200, 256, 0, stream>>>(x, xbb);
  k_prep<<<1552, 256, 0, stream>>>(w_out, w_k, w_q, w_ff, w_t, b_q, wb, wkqb,
                                   wffb, wbt, qbb);
  k_qkg<<<dim3(900, 2), 256, 0, stream>>>(xbb, wkqb, b_k, b_q, kbb, qbb);
  k_scores<<<128, 512, 0, stream>>>(kbb, qbb, alphas, att0, attTb);
  k_attn3<<<dim3(144, 16), 256, 0, stream>>>(x, xbb, attTb, wb, b_out, g_out,
                                             be_out, m_out, v_out, wffb, b_ff,
                                             g_ff, be_ff, m_ff, v_ff, y2b);
  k_tconv<<<dim3(57, 16), 256, 0, stream>>>(y2b, x, wbt, b_t, g_t, be_t, m_t,
                                            v_t, outp);
}

// Round 20
// 356.877 us; speedup vs baseline: 1.0972x; 1.0972x over previous
//
#include <hip/hip_runtime.h>

// SSHA block. Round 20 = revert to round-18 configuration (best measured,
// 358 us). Round-19's LDS-free k_tconv regressed (poor coalescing + 7x
// window re-fetch > L1): tconv's A-reuse justifies LDS staging.
// Shapes: N=16, T=288, V=25, C=128, S=8, IC=16, W=3, U=75, TP=290.

#define NN 16
#define TT 288
#define VV 25
#define CC 128
#define SS 8
#define UU 75
#define TP 290
#define EPSF 1e-5f

typedef __attribute__((ext_vector_type(8))) short bf16x8;
typedef __attribute__((ext_vector_type(4))) float f32x4;

static __device__ __forceinline__ ushort f2bf(float f) {
  uint u = __float_as_uint(f);
  u = (u + 0x7FFFu + ((u >> 16) & 1u)) >> 16;
  return (ushort)u;
}
static __device__ __forceinline__ float bf2f(ushort u) {
  return __uint_as_float((uint)u << 16);
}

// ---------------- K-1: x -> bf16 (once) ----------------
__global__ __launch_bounds__(256) void k_xcvt(const float* __restrict__ x,
                                              ushort* __restrict__ xb) {
  size_t i = (size_t)blockIdx.x * 256 + threadIdx.x;  // 1,843,200 thr x 8 el
  const float4* xp = (const float4*)x + i * 2;
  float4 a0 = xp[0], a1 = xp[1];
  uint4 pk;
  pk.x = (uint)f2bf(a0.x) | ((uint)f2bf(a0.y) << 16);
  pk.y = (uint)f2bf(a0.z) | ((uint)f2bf(a0.w) << 16);
  pk.z = (uint)f2bf(a1.x) | ((uint)f2bf(a1.y) << 16);
  pk.w = (uint)f2bf(a1.z) | ((uint)f2bf(a1.w) << 16);
  *(uint4*)&xb[i * 8] = pk;
}

// ---------------- K0: all weight converts + qb pad rows ----------------
__global__ __launch_bounds__(256) void k_prep(
    const float* __restrict__ w_out, const float* __restrict__ w_k,
    const float* __restrict__ w_q, const float* __restrict__ w_ff,
    const float* __restrict__ w_t, const float* __restrict__ b_q,
    ushort* __restrict__ wb, ushort* __restrict__ wkqb,
    ushort* __restrict__ wffb, ushort* __restrict__ wbt,
    ushort* __restrict__ qb) {
  int i = blockIdx.x * 256 + threadIdx.x;  // 397312 total
  if (i < 131072) {
    int j = i >> 7, c = i & 127;
    int s = j >> 7, o = j & 127;
    wb[i] = f2bf(w_out[(o << 10) + (s << 7) + c]);
  } else if (i < 163840) {
    int j = i - 131072;
    if (j < 16384) wkqb[j] = f2bf(w_k[j]);
    else wkqb[j] = f2bf(w_q[j - 16384]);
  } else if (i < 180224) {
    int j = i - 163840;
    wffb[j] = f2bf(w_ff[j]);
  } else if (i < 294912) {
    int j = i - 180224;
    int o = j / 896;
    int rem = j - o * 896;
    int c = rem / 7, kt = rem - c * 7;
    wbt[o * 896 + kt * 128 + c] = f2bf(w_t[j]);
  } else {
    int j = i - 294912;  // 102400: qb bias-only pad rows (tp=0, 289)
    int o = j & 127;
    int r = j >> 7;
    int v = r % 25;
    int e = (r / 25) & 1;
    int n = r / 50;
    int tp = e ? 289 : 0;
    qb[((size_t)((n * TP + tp) * VV + v) << 7) + o] = f2bf(b_q[o]);
  }
}

// ---------------- K1: k/q 1x1 convs as bf16 MFMA GEMM (LDS-free, xb input) ----------------
__global__ __launch_bounds__(256) void k_qkg(
    const ushort* __restrict__ xb, const ushort* __restrict__ wkqb,
    const float* __restrict__ b_k, const float* __restrict__ b_q,
    ushort* __restrict__ kb, ushort* __restrict__ qb) {
  const int gm0 = blockIdx.x << 7, by = blockIdx.y;
  const int tid = threadIdx.x;
  const int lane = tid & 63, wid = tid >> 6;
  const int wm = wid >> 1, wn = wid & 1;
  const int l15 = lane & 15, l4 = lane >> 4;
  const ushort* wsrc = wkqb + by * 16384;
  f32x4 acc[4][4] = {};
#pragma unroll
  for (int g = 0; g < 4; ++g) {
    const int k0 = g * 32 + l4 * 8;
    bf16x8 af[4], bfr[4];
#pragma unroll
    for (int mi = 0; mi < 4; ++mi)
      af[mi] = *(const bf16x8*)&xb[((size_t)(gm0 + wm * 64 + mi * 16 + l15))
                                       * 128 + k0];
#pragma unroll
    for (int ni = 0; ni < 4; ++ni)
      bfr[ni] = *(const bf16x8*)&wsrc[(wn * 64 + ni * 16 + l15) * 128 + k0];
#pragma unroll
    for (int mi = 0; mi < 4; ++mi)
#pragma unroll
      for (int ni = 0; ni < 4; ++ni)
        acc[mi][ni] = __builtin_amdgcn_mfma_f32_16x16x32_bf16(
            af[mi], bfr[ni], acc[mi][ni], 0, 0, 0);
  }
  const float* bias = by ? b_q : b_k;
#pragma unroll
  for (int ni = 0; ni < 4; ++ni) {
    int col = wn * 64 + ni * 16 + l15;
    float bb = bias[col];
#pragma unroll
    for (int mi = 0; mi < 4; ++mi) {
#pragma unroll
      for (int reg = 0; reg < 4; ++reg) {
        int row = gm0 + wm * 64 + mi * 16 + (l4 << 2) + reg;
        ushort val = f2bf(acc[mi][ni][reg] + bb);
        if (by == 0) {
          kb[((size_t)row << 7) + col] = val;
        } else {
          int n = row / 7200;
          qb[((size_t)(row + n * 50 + 25) << 7) + col] = val;
        }
      }
    }
  }
}

// ---------------- K2: scores (bf16 MFMA) + fused softmax -> attTb bf16 ----------------
// attTb[n][s][v(25)][u'(96)] with u' = w*32+vp, zero at vp>=25.
__global__ __launch_bounds__(512) void k_scores(
    const ushort* __restrict__ kb, const ushort* __restrict__ qb,
    const float* __restrict__ alphas, const float* __restrict__ att0,
    ushort* __restrict__ attTb) {
  __shared__ float red[8][2640];  // [wave][u(80) * 33 + v(32)]
  __shared__ float scl[1875];
  __shared__ float mx[25];
  __shared__ float den[25];
  const int bx = blockIdx.x;
  const int n = bx >> 3, s = bx & 7;
  const int tid = threadIdx.x;
  const int lane = tid & 63, wid = tid >> 6;
  const int l15 = lane & 15, l4 = lane >> 4;
  const int dt = l4 >> 1;
  const int sic = s * 16 + (l4 & 1) * 8;
  int qoff[5];
#pragma unroll
  for (int tu = 0; tu < 5; ++tu) {
    int u = tu * 16 + l15;
    int w = u / 25, vp = u - w * 25;
    qoff[tu] = (w * 25 + vp) * 128 + sic;
  }
  const bool qv4 = (64 + l15) < 75;
  const bool kv1 = (16 + l15) < 25;
  int koff0 = l15 * 128 + sic;
  int koff1 = (16 + l15) * 128 + sic;
  const ushort* qbase = qb + (size_t)n * 928000 + (size_t)dt * 3200;
  const ushort* kbase = kb + (size_t)n * 921600 + (size_t)dt * 3200;
  f32x4 acc[5][2] = {};
  const bf16x8 zf = {};
  for (int kk = wid; kk < 144; kk += 8) {
    const ushort* qp = qbase + kk * 6400;
    const ushort* kp = kbase + kk * 6400;
    bf16x8 a[5], b[2];
#pragma unroll
    for (int tu = 0; tu < 4; ++tu) a[tu] = *(const bf16x8*)(qp + qoff[tu]);
    a[4] = qv4 ? *(const bf16x8*)(qp + qoff[4]) : zf;
    b[0] = *(const bf16x8*)(kp + koff0);
    b[1] = kv1 ? *(const bf16x8*)(kp + koff1) : zf;
#pragma unroll
    for (int tu = 0; tu < 5; ++tu)
#pragma unroll
      for (int tv = 0; tv < 2; ++tv)
        acc[tu][tv] = __builtin_amdgcn_mfma_f32_16x16x32_bf16(
            a[tu], b[tv], acc[tu][tv], 0, 0, 0);
  }
#pragma unroll
  for (int tu = 0; tu < 5; ++tu)
#pragma unroll
    for (int tv = 0; tv < 2; ++tv) {
#pragma unroll
      for (int reg = 0; reg < 4; ++reg)
        red[wid][(tu * 16 + l4 * 4 + reg) * 33 + tv * 16 + l15] =
            acc[tu][tv][reg];
    }
  __syncthreads();
  const float inv = 1.0f / 4608.0f;
  for (int i = tid; i < 1875; i += 512) {
    int u = i / 25, v = i - u * 25;
    float a = 0.f;
#pragma unroll
    for (int w = 0; w < 8; ++w) a += red[w][u * 33 + v];
    scl[i] = a * inv;
  }
  __syncthreads();
  if (tid < 25) {
    float m = -1e30f;
    for (int u = 0; u < 75; ++u) m = fmaxf(m, scl[u * 25 + tid]);
    float d = 0.f;
    for (int u = 0; u < 75; ++u) d += expf(scl[u * 25 + tid] - m);
    mx[tid] = m;
    den[tid] = d;
  }
  __syncthreads();
  const float alpha = alphas[s];
  ushort* op = attTb + (size_t)bx * 2400;
  for (int i = tid; i < 2400; i += 512) {
    int v = i / 96, u = i - v * 96;
    int w = u >> 5, vp = u & 31;
    float val = 0.f;
    if (vp < 25) {
      int uo = w * 25 + vp;
      val = expf(scl[uo * 25 + v] - mx[v]) / den[v] * alpha +
            att0[(s * 75 + uo) * 25 + v];
    }
    op[i] = f2bf(val);
  }
}

// ---------------- K3: attention-apply + out conv + FF conv (triple MFMA, TB=2) ----------------
__global__ __launch_bounds__(256, 3) void k_attn3(
    const float* __restrict__ x, const ushort* __restrict__ xb,
    const ushort* __restrict__ attTb, const ushort* __restrict__ wb,
    const float* __restrict__ b_out, const float* __restrict__ g_out,
    const float* __restrict__ beta_out, const float* __restrict__ m_out,
    const float* __restrict__ v_out, const ushort* __restrict__ wffb,
    const float* __restrict__ b_ff, const float* __restrict__ g_ff,
    const float* __restrict__ beta_ff, const float* __restrict__ m_ff,
    const float* __restrict__ v_ff, ushort* __restrict__ y2b) {
  __shared__ __align__(16) uint4 Xt4[16 * 129];  // [chunk][c pad129]
  __shared__ __align__(16) ushort Yl[2][32 * 136];
  const int t0 = blockIdx.x * 2, n = blockIdx.y;
  const int tid = threadIdx.x;
  // stage Xt from xb: chunk = r*4 + vp0/8 (r = t-row, tr = t0+r-1).
  for (int i = tid; i < 2048; i += 256) {
    int c = i & 127, chunk = i >> 7;
    int r = chunk >> 2, vp0 = (chunk & 3) * 8;
    int tr = t0 + r - 1;
    bool valid = (tr >= 0 && tr < TT);
    const ushort* xr = xb + (((size_t)(n * TT + tr) * VV)) * 128 + c;
    ushort p[8];
#pragma unroll
    for (int j = 0; j < 8; ++j) {
      int vp = vp0 + j;
      p[j] = (valid && vp < 25) ? xr[vp * 128] : (ushort)0;
    }
    uint4 pk;
    pk.x = (uint)p[0] | ((uint)p[1] << 16);
    pk.y = (uint)p[2] | ((uint)p[3] << 16);
    pk.z = (uint)p[4] | ((uint)p[5] << 16);
    pk.w = (uint)p[6] | ((uint)p[7] << 16);
    Xt4[chunk * 129 + c] = pk;
  }
  __syncthreads();
  const int lane = tid & 63, wid = tid >> 6;
  const int l15 = lane & 15, l4 = lane >> 4;
  const bf16x8 zf = {};
  f32x4 accO[2][2][2] = {};  // [tt][mi(o)][nj(v)]
  const ushort* Avn = attTb + (size_t)n * 19200;
  const int c0r = wid * 32 + l15, c1r = wid * 32 + 16 + l15;

  // step1: accY[tt][cmi][vnj] = D[c][v], A = X rows c, B = Av rows v.
  auto step1 = [&](int s, f32x4 (&accY)[2][2][2]) {
    const ushort* AvS = Avn + s * 2400;
#pragma unroll
    for (int ks = 0; ks < 3; ++ks) {
      int u0 = ks * 32 + l4 * 8;
      bf16x8 av0 = *(const bf16x8*)&AvS[l15 * 96 + u0];
      int r1 = 16 + l15;
      bf16x8 av1 = *(const bf16x8*)&AvS[(r1 <= 24 ? r1 : 24) * 96 + u0];
      if (l15 > 8) av1 = zf;  // v >= 25 -> zero row
#pragma unroll
      for (int tt = 0; tt < 2; ++tt) {
        int ch = (tt + ks) * 4 + l4;
        bf16x8 xb0 = *(const bf16x8*)&Xt4[ch * 129 + c0r];
        bf16x8 xb1 = *(const bf16x8*)&Xt4[ch * 129 + c1r];
        accY[tt][0][0] = __builtin_amdgcn_mfma_f32_16x16x32_bf16(xb0, av0, accY[tt][0][0], 0, 0, 0);
        accY[tt][0][1] = __builtin_amdgcn_mfma_f32_16x16x32_bf16(xb0, av1, accY[tt][0][1], 0, 0, 0);
        accY[tt][1][0] = __builtin_amdgcn_mfma_f32_16x16x32_bf16(xb1, av0, accY[tt][1][0], 0, 0, 0);
        accY[tt][1][1] = __builtin_amdgcn_mfma_f32_16x16x32_bf16(xb1, av1, accY[tt][1][1], 0, 0, 0);
      }
    }
  };

  f32x4 accYc[2][2][2] = {};
  step1(0, accYc);
#pragma unroll
  for (int s = 0; s < 8; ++s) {
    __syncthreads();  // previous step-2 readers done with Yl
#pragma unroll
    for (int tt = 0; tt < 2; ++tt)
#pragma unroll
      for (int cmi = 0; cmi < 2; ++cmi)
#pragma unroll
        for (int vnj = 0; vnj < 2; ++vnj) {
          ushort4 p;
          p.x = f2bf(accYc[tt][cmi][vnj][0]);
          p.y = f2bf(accYc[tt][cmi][vnj][1]);
          p.z = f2bf(accYc[tt][cmi][vnj][2]);
          p.w = f2bf(accYc[tt][cmi][vnj][3]);
          *(ushort4*)&Yl[tt][(vnj * 16 + l15) * 136 + wid * 32 + cmi * 16 +
                             (l4 << 2)] = p;
        }
    __syncthreads();
    // pipelined: step1(s+1) + step2(s) between barriers (independent work)
    __builtin_amdgcn_s_setprio(1);
    f32x4 accYn[2][2][2] = {};
    if (s < 7) step1(s + 1, accYn);
    const ushort* wS = wb + s * 16384;
#pragma unroll
    for (int kc = 0; kc < 4; ++kc) {
      int c0 = kc * 32 + l4 * 8;
      bf16x8 wf0 = *(const bf16x8*)&wS[(wid * 32 + l15) * 128 + c0];
      bf16x8 wf1 = *(const bf16x8*)&wS[(wid * 32 + 16 + l15) * 128 + c0];
#pragma unroll
      for (int tt = 0; tt < 2; ++tt) {
        bf16x8 yb0 = *(const bf16x8*)&Yl[tt][l15 * 136 + c0];
        bf16x8 yb1 = *(const bf16x8*)&Yl[tt][(16 + l15) * 136 + c0];
        accO[tt][0][0] = __builtin_amdgcn_mfma_f32_16x16x32_bf16(wf0, yb0, accO[tt][0][0], 0, 0, 0);
        accO[tt][0][1] = __builtin_amdgcn_mfma_f32_16x16x32_bf16(wf0, yb1, accO[tt][0][1], 0, 0, 0);
        accO[tt][1][0] = __builtin_amdgcn_mfma_f32_16x16x32_bf16(wf1, yb0, accO[tt][1][0], 0, 0, 0);
        accO[tt][1][1] = __builtin_amdgcn_mfma_f32_16x16x32_bf16(wf1, yb1, accO[tt][1][1], 0, 0, 0);
      }
    }
    __builtin_amdgcn_s_setprio(0);
#pragma unroll
    for (int tt = 0; tt < 2; ++tt)
#pragma unroll
      for (int mi = 0; mi < 2; ++mi)
#pragma unroll
        for (int nj = 0; nj < 2; ++nj)
          accYc[tt][mi][nj] = accYn[tt][mi][nj];
  }
  // ---- y1 epilogue: BN + leaky(x + .), write bf16 to Yl (v>=25 rows = 0) ----
  __syncthreads();  // last step-2 Yl reads complete
#pragma unroll
  for (int tt = 0; tt < 2; ++tt) {
    int t = t0 + tt;
#pragma unroll
    for (int nj = 0; nj < 2; ++nj) {
      int v = nj * 16 + l15;
      ushort4 pv[2];
      if (v < 25) {
        size_t rowbase = (((size_t)(n * TT + t) * VV + v)) * 128 + wid * 32;
#pragma unroll
        for (int mi = 0; mi < 2; ++mi) {
          int ob = mi * 16 + (l4 << 2);
          int og = wid * 32 + ob;
          float4 gg = *(const float4*)&g_out[og];
          float4 vv = *(const float4*)&v_out[og];
          float4 mm = *(const float4*)&m_out[og];
          float4 be = *(const float4*)&beta_out[og];
          float4 bo = *(const float4*)&b_out[og];
          float4 xv = *(const float4*)&x[rowbase + ob];
          float s1, a;
          s1 = gg.x * rsqrtf(vv.x + EPSF);
          a = (accO[tt][mi][nj][0] + bo.x) * s1 + (be.x - mm.x * s1) + xv.x;
          pv[mi].x = f2bf(a > 0.f ? a : 0.1f * a);
          s1 = gg.y * rsqrtf(vv.y + EPSF);
          a = (accO[tt][mi][nj][1] + bo.y) * s1 + (be.y - mm.y * s1) + xv.y;
          pv[mi].y = f2bf(a > 0.f ? a : 0.1f * a);
          s1 = gg.z * rsqrtf(vv.z + EPSF);
          a = (accO[tt][mi][nj][2] + bo.z) * s1 + (be.z - mm.z * s1) + xv.z;
          pv[mi].z = f2bf(a > 0.f ? a : 0.1f * a);
          s1 = gg.w * rsqrtf(vv.w + EPSF);
          a = (accO[tt][mi][nj][3] + bo.w) * s1 + (be.w - mm.w * s1) + xv.w;
          pv[mi].w = f2bf(a > 0.f ? a : 0.1f * a);
        }
      } else {
        pv[0] = make_ushort4(0, 0, 0, 0);
        pv[1] = make_ushort4(0, 0, 0, 0);
      }
#pragma unroll
      for (int mi = 0; mi < 2; ++mi)
        *(ushort4*)&Yl[tt][v * 136 + wid * 32 + mi * 16 + (l4 << 2)] = pv[mi];
    }
  }
  __syncthreads();
  // ---- step 3: FF = W_ff . y1 (K=128) ----
  f32x4 accF[2][2][2] = {};  // [tt][mi(o)][nj(v)]
#pragma unroll
  for (int kc = 0; kc < 4; ++kc) {
    int c0 = kc * 32 + l4 * 8;
    bf16x8 wf0 = *(const bf16x8*)&wffb[(wid * 32 + l15) * 128 + c0];
    bf16x8 wf1 = *(const bf16x8*)&wffb[(wid * 32 + 16 + l15) * 128 + c0];
#pragma unroll
    for (int tt = 0; tt < 2; ++tt) {
      bf16x8 yb0 = *(const bf16x8*)&Yl[tt][l15 * 136 + c0];
      bf16x8 yb1 = *(const bf16x8*)&Yl[tt][(16 + l15) * 136 + c0];
      accF[tt][0][0] = __builtin_amdgcn_mfma_f32_16x16x32_bf16(wf0, yb0, accF[tt][0][0], 0, 0, 0);
      accF[tt][0][1] = __builtin_amdgcn_mfma_f32_16x16x32_bf16(wf0, yb1, accF[tt][0][1], 0, 0, 0);
      accF[tt][1][0] = __builtin_amdgcn_mfma_f32_16x16x32_bf16(wf1, yb0, accF[tt][1][0], 0, 0, 0);
      accF[tt][1][1] = __builtin_amdgcn_mfma_f32_16x16x32_bf16(wf1, yb1, accF[tt][1][1], 0, 0, 0);
    }
  }
  // ---- ff epilogue: y2b = bf16(leaky(x + BN_ff(FF + b_ff))) ----
#pragma unroll
  for (int tt = 0; tt < 2; ++tt) {
    int t = t0 + tt;
#pragma unroll
    for (int nj = 0; nj < 2; ++nj) {
      int v = nj * 16 + l15;
      if (v < 25) {
        size_t rowbase = (((size_t)(n * TT + t) * VV + v)) * 128 + wid * 32;
#pragma unroll
        for (int mi = 0; mi < 2; ++mi) {
          int ob = mi * 16 + (l4 << 2);
          int og = wid * 32 + ob;
          float4 gg = *(const float4*)&g_ff[og];
          float4 vv = *(const float4*)&v_ff[og];
          float4 mm = *(const float4*)&m_ff[og];
          float4 be = *(const float4*)&beta_ff[og];
          float4 bo = *(const float4*)&b_ff[og];
          float4 xv = *(const float4*)&x[rowbase + ob];
          ushort4 r;
          float s1, a;
          s1 = gg.x * rsqrtf(vv.x + EPSF);
          a = (accF[tt][mi][nj][0] + bo.x) * s1 + (be.x - mm.x * s1) + xv.x;
          r.x = f2bf(a > 0.f ? a : 0.1f * a);
          s1 = gg.y * rsqrtf(vv.y + EPSF);
          a = (accF[tt][mi][nj][1] + bo.y) * s1 + (be.y - mm.y * s1) + xv.y;
          r.y = f2bf(a > 0.f ? a : 0.1f * a);
          s1 = gg.z * rsqrtf(vv.z + EPSF);
          a = (accF[tt][mi][nj][2] + bo.z) * s1 + (be.z - mm.z * s1) + xv.z;
          r.z = f2bf(a > 0.f ? a : 0.1f * a);
          s1 = gg.w * rsqrtf(vv.w + EPSF);
          a = (accF[tt][mi][nj][3] + bo.w) * s1 + (be.w - mm.w * s1) + xv.w;
          r.w = f2bf(a > 0.f ? a : 0.1f * a);
          *(ushort4*)&y2b[rowbase + ob] = r;
        }
      }
    }
  }
}

// ---------------- K5: temporal conv as bf16 MFMA GEMM (LDS-staged, y2b input) ----------------
__global__ __launch_bounds__(256, 2) void k_tconv(
    const ushort* __restrict__ y2b, const float* __restrict__ x,
    const ushort* __restrict__ wbt, const float* __restrict__ b_t,
    const float* __restrict__ g_t, const float* __restrict__ beta_t,
    const float* __restrict__ m_t, const float* __restrict__ v_t,
    float* __restrict__ out) {
  __shared__ __align__(16) uint4 As[280 * 16];  // [row][16B-chunk], ^(row&7)
  const int n = blockIdx.y;
  const int r0 = blockIdx.x << 7;
  const int tid = threadIdx.x;
  const ushort* y2n = y2b + ((size_t)n * 7200) * 128;
  for (int i = tid; i < 278 * 16; i += 256) {
    int rl = i >> 4, cc = i & 15;
    int g = r0 - 75 + rl;
    uint4 pk = make_uint4(0u, 0u, 0u, 0u);
    if (g >= 0 && g < 7200)
      pk = *(const uint4*)&y2n[(size_t)g * 128 + (cc << 3)];
    As[(rl << 4) + (cc ^ (rl & 7))] = pk;
  }
  __syncthreads();
  const int lane = tid & 63, wid = tid >> 6;
  const int wm = wid >> 1, wn = wid & 1;
  const int l15 = lane & 15, l4 = lane >> 4;
  f32x4 acc[4][4] = {};
  for (int kt = 0; kt < 7; ++kt) {
    bf16x8 bfr[4][4];
#pragma unroll
    for (int ni = 0; ni < 4; ++ni) {
      const ushort* bp =
          wbt + (size_t)(wn * 64 + ni * 16 + l15) * 896 + kt * 128 + l4 * 8;
#pragma unroll
      for (int cc0 = 0; cc0 < 4; ++cc0)
        bfr[ni][cc0] = *(const bf16x8*)(bp + cc0 * 32);
    }
#pragma unroll
    for (int cc0 = 0; cc0 < 4; ++cc0) {
      bf16x8 af[4];
#pragma unroll
      for (int mi = 0; mi < 4; ++mi) {
        int rl = wm * 64 + mi * 16 + l15 + 25 * kt;
        af[mi] = *(const bf16x8*)&As[(rl << 4) + ((cc0 * 4 + l4) ^ (rl & 7))];
      }
#pragma unroll
      for (int mi = 0; mi < 4; ++mi)
#pragma unroll
        for (int ni = 0; ni < 4; ++ni)
          acc[mi][ni] = __builtin_amdgcn_mfma_f32_16x16x32_bf16(
              af[mi], bfr[ni][cc0], acc[mi][ni], 0, 0, 0);
    }
  }
#pragma unroll
  for (int ni = 0; ni < 4; ++ni) {
    int o = wn * 64 + ni * 16 + l15;
    float s1 = g_t[o] * rsqrtf(v_t[o] + EPSF);
    float sh = beta_t[o] - m_t[o] * s1;
    float bb = b_t[o];
#pragma unroll
    for (int mi = 0; mi < 4; ++mi) {
#pragma unroll
      for (int reg = 0; reg < 4; ++reg) {
        int grow = r0 + wm * 64 + mi * 16 + (l4 << 2) + reg;
        if (grow < 7200) {
          size_t idx = (((size_t)n * 7200 + grow) << 7) + o;
          float z = (acc[mi][ni][reg] + bb) * s1 + sh;
          z += bf2f(y2b[idx]);
          z = z > 0.f ? z : 0.1f * z;
          z += x[idx];
          out[idx] = z > 0.f ? z : 0.f;
        }
      }
    }
  }
}

extern "C" void kernel_launch(void* const* d_in, const int* in_sizes, int n_in,
                              void* d_out, int out_size, void* d_ws, size_t ws_size,
                              hipStream_t stream) {
  const float* x      = (const float*)d_in[0];
  const float* w_k    = (const float*)d_in[1];
  const float* b_k    = (const float*)d_in[2];
  const float* w_q    = (const float*)d_in[3];
  const float* b_q    = (const float*)d_in[4];
  const float* alphas = (const float*)d_in[5];
  const float* att0   = (const float*)d_in[6];
  const float* w_out  = (const float*)d_in[7];
  const float* b_out  = (const float*)d_in[8];
  const float* g_out  = (const float*)d_in[9];
  const float* be_out = (const float*)d_in[10];
  const float* m_out  = (const float*)d_in[11];
  const float* v_out  = (const float*)d_in[12];
  const float* w_ff   = (const float*)d_in[13];
  const float* b_ff   = (const float*)d_in[14];
  const float* g_ff   = (const float*)d_in[15];
  const float* be_ff  = (const float*)d_in[16];
  const float* m_ff   = (const float*)d_in[17];
  const float* v_ff   = (const float*)d_in[18];
  const float* w_t    = (const float*)d_in[19];
  const float* b_t    = (const float*)d_in[20];
  const float* g_t    = (const float*)d_in[21];
  const float* be_t   = (const float*)d_in[22];
  const float* m_t    = (const float*)d_in[23];
  const float* v_t    = (const float*)d_in[24];

  float* ws = (float*)d_ws;
  // Region plan (floats), total 32,108,288 = round-1 proven footprint:
  float* qfull = ws;               // [0, 14848000)   qb bf16
  float* kfull = ws + 14848000;    // [.., +14745600) kb bf16 (lo, -> y2b) + xb (hi)
  float* part  = ws + 29593600;    // [.., +2160000)  wb/wkqb/wffb bf16
  float* attr  = ws + 31753600;    // [.., +240000)   attTb bf16 (307200 sh)
  float* wtr   = ws + 31993600;    // [.., +114688)   wbt bf16
  ushort* qbb   = (ushort*)qfull;
  ushort* kbb   = (ushort*)kfull;              // 14,745,600 shorts
  ushort* xbb   = (ushort*)kfull + 14745600;   // 14,745,600 shorts
  ushort* y2b   = kbb;  // kb dead after k_scores
  ushort* wb    = (ushort*)part;            // 131072 shorts
  ushort* wkqb  = (ushort*)part + 131072;   //  32768 shorts
  ushort* wffb  = (ushort*)part + 163840;   //  16384 shorts
  ushort* attTb = (ushort*)attr;
  ushort* wbt   = (ushort*)wtr;
  float* outp = (float*)d_out;

  k_xcvt<<<7200, 256, 0, stream>>>(x, xbb);
  k_prep<<<1552, 256, 0, stream>>>(w_out, w_k, w_q, w_ff, w_t, b_q, wb, wkqb,
                                   wffb, wbt, qbb);
  k_qkg<<<dim3(900, 2), 256, 0, stream>>>(xbb, wkqb, b_k, b_q, kbb, qbb);
  k_scores<<<128, 512, 0, stream>>>(kbb, qbb, alphas, att0, attTb);
  k_attn3<<<dim3(144, 16), 256, 0, stream>>>(x, xbb, attTb, wb, b_out, g_out,
                                             be_out, m_out, v_out, wffb, b_ff,
                                             g_ff, be_ff, m_ff, v_ff, y2b);
  k_tconv<<<dim3(57, 16), 256, 0, stream>>>(y2b, x, wbt, b_t, g_t, be_t, m_t,
                                            v_t, outp);
}